// Round 2
// baseline (267.406 us; speedup 1.0000x reference)
//
#include <hip/hip_runtime.h>

// Linear attention, all-fp32, software-pipelined (1 barrier/tile, loads issued
// AFTER the barrier and consumed AFTER the compute so the __syncthreads vmcnt(0)
// drain never exposes HBM latency).
// Per bh: KV[d][c] = sum_s ke[s][d]*ve[s][c]/S ; ksum[d] = sum_s ke[s][d]
//         out[l][c] = S * (qe.KV)[l][c] / (qe.ksum[l] + 1e-6)

#define S_LEN 8192
#define NBH 32
#define KVSTRIDE 4160   // 4096 KV + 64 ksum per (bh, chunk)
#define NCHUNK 16       // k1: 512 blocks (2/CU, all co-resident), 8 tiles each
#define K3_XB 16        // k3: 16 blocks per bh -> 512 blocks, 8 chunks each

typedef __attribute__((ext_vector_type(4))) float f32x4;

__device__ __forceinline__ float elu1(float x) {
  return x > 0.0f ? (x + 1.0f) : __expf(x);
}

// ---------------- Phase 1: partial KV + ksum over a segment of S ----------------
// Thread tile 4(d) x 4(c). LDS stride 64: ke reads 16-lane broadcast conflict-free,
// ve reads 2-way (free). Double-buffered LDS, single barrier per tile.
__global__ __launch_bounds__(256) void k1_partial(
    const float* __restrict__ kin, const float* __restrict__ vin,
    const int* __restrict__ kv_mask, float* __restrict__ partials, int seg_rows) {
  __shared__ float ke_lds[2][64 * 64];
  __shared__ float ve_lds[2][64 * 64];
  const int tid = threadIdx.x;
  const int seg = blockIdx.x, bh = blockIdx.y, b = bh >> 3;   // H=8
  const int rbase = seg * seg_rows;
  const int dg = tid >> 4, cg = tid & 15;   // dg doubles as staging row-group
  const float* kbase = kin + (size_t)bh * S_LEN * 64;
  const float* vbase = vin + (size_t)bh * S_LEN * 64;
  const int* mbase = kv_mask + b * S_LEN;

  f32x4 kr[4], vr[4];
  float mr[4];
  float acc[4][4];
#pragma unroll
  for (int i = 0; i < 4; ++i)
#pragma unroll
    for (int j = 0; j < 4; ++j) acc[i][j] = 0.f;
  f32x4 ksump = {0.f, 0.f, 0.f, 0.f};

#define LOAD_T(r0_)                                                    \
  {                                                                    \
    const float* kp_ = kbase + (size_t)(r0_) * 64;                     \
    const float* vp_ = vbase + (size_t)(r0_) * 64;                     \
    _Pragma("unroll")                                                  \
    for (int i_ = 0; i_ < 4; ++i_) {                                   \
      int f_ = tid + 256 * i_;                                         \
      kr[i_] = *(const f32x4*)(kp_ + (size_t)f_ * 4);                  \
      vr[i_] = *(const f32x4*)(vp_ + (size_t)f_ * 4);                  \
      mr[i_] = mbase[(r0_) + dg + 16 * i_] ? 1.0f : 0.0f;              \
    }                                                                  \
  }

#define STORE_T(buf_)                                                  \
  {                                                                    \
    _Pragma("unroll")                                                  \
    for (int i_ = 0; i_ < 4; ++i_) {                                   \
      int row_ = dg + 16 * i_;                                         \
      float m_ = mr[i_];                                               \
      float mv_ = m_ * (1.0f / 8192.0f);                               \
      f32x4 ke4_, ve4_;                                                \
      _Pragma("unroll")                                                \
      for (int j_ = 0; j_ < 4; ++j_) {                                 \
        ke4_[j_] = elu1(kr[i_][j_]) * m_;                              \
        ve4_[j_] = vr[i_][j_] * mv_;                                   \
      }                                                                \
      ksump += ke4_;                                                   \
      *(f32x4*)&ke_lds[buf_][row_ * 64 + cg * 4] = ke4_;               \
      *(f32x4*)&ve_lds[buf_][row_ * 64 + cg * 4] = ve4_;               \
    }                                                                  \
  }

#define COMPUTE_T(buf_)                                                \
  {                                                                    \
    _Pragma("unroll 4")                                                \
    for (int s_ = 0; s_ < 64; ++s_) {                                  \
      f32x4 kd_ = *(const f32x4*)&ke_lds[buf_][s_ * 64 + dg * 4];      \
      f32x4 vc_ = *(const f32x4*)&ve_lds[buf_][s_ * 64 + cg * 4];      \
      _Pragma("unroll")                                                \
      for (int i_ = 0; i_ < 4; ++i_)                                   \
        _Pragma("unroll")                                              \
        for (int j_ = 0; j_ < 4; ++j_)                                 \
          acc[i_][j_] = fmaf(kd_[i_], vc_[j_], acc[i_][j_]);           \
    }                                                                  \
  }

  const int ntiles = seg_rows >> 6;
  LOAD_T(rbase)
  STORE_T(0)                      // prologue: only exposed vmcnt wait
  for (int t = 0; t < ntiles; ++t) {
    __syncthreads();              // nothing in flight here — no wasted drain
    if (t + 1 < ntiles) LOAD_T(rbase + (t + 1) * 64)   // issue next tile
    COMPUTE_T(t & 1)              // ~2000 cyc, covers the loads above
    if (t + 1 < ntiles) STORE_T((t + 1) & 1)           // consume loads post-compute
  }

  // store partial KV [d][c] fp32 (coalesced float4)
  float* p = partials + ((size_t)bh * gridDim.x + seg) * KVSTRIDE;
#pragma unroll
  for (int i = 0; i < 4; ++i) {
    f32x4 o;
#pragma unroll
    for (int j = 0; j < 4; ++j) o[j] = acc[i][j];
    *(f32x4*)&p[(dg * 4 + i) * 64 + cg * 4] = o;
  }
  // ksum: reduce per-thread column partials (thread covers cols cg*4..+3)
  __syncthreads();
  *(f32x4*)&ke_lds[0][tid * 4] = ksump;
  __syncthreads();
  if (tid < 64) {
    float s = 0.f;
#pragma unroll
    for (int g = 0; g < 16; ++g)
      s += ke_lds[0][(g * 16 + (tid >> 2)) * 4 + (tid & 3)];
    p[4096 + tid] = s;
  }
#undef LOAD_T
#undef STORE_T
#undef COMPUTE_T
}

// ---------------- Phase 2: reduce partials -> fp32 KV + ksum ----------------
__global__ __launch_bounds__(256) void k2_reduce(
    const float* __restrict__ partials, float* __restrict__ kvg, int nchunk) {
  const int idx = blockIdx.x * 256 + threadIdx.x;
  if (idx >= NBH * KVSTRIDE) return;
  const int bh = idx / KVSTRIDE;
  const int e = idx - bh * KVSTRIDE;
  const float* p = partials + (size_t)bh * nchunk * KVSTRIDE + e;
  float s0 = 0.f, s1 = 0.f, s2 = 0.f, s3 = 0.f;
  int c = 0;
  for (; c + 4 <= nchunk; c += 4) {
    s0 += p[(size_t)(c + 0) * KVSTRIDE];
    s1 += p[(size_t)(c + 1) * KVSTRIDE];
    s2 += p[(size_t)(c + 2) * KVSTRIDE];
    s3 += p[(size_t)(c + 3) * KVSTRIDE];
  }
  for (; c < nchunk; ++c) s0 += p[(size_t)c * KVSTRIDE];
  kvg[idx] = (s0 + s1) + (s2 + s3);
}

// ---------------- Phase 3: out = S * (qe.KV) / (qe.ksum + 1e-6) ----------------
// 512 blocks, 8 chunks of 64 rows each. KV + ksum staged in LDS once per block.
// qe double-buffered (stride 68: 16B-aligned, bank-spread). Denominator folded
// into the compute loop (den[l] += qe*ks) — no reduction barrier needed.
__global__ __launch_bounds__(256) void k3_out(
    const float* __restrict__ qin, const int* __restrict__ q_mask,
    const float* __restrict__ kvg, float* __restrict__ out) {
  __shared__ float kv_lds[64 * 64];
  __shared__ float qe_lds[2][64 * 68];
  __shared__ float ks_lds[64];
  const int tid = threadIdx.x;
  const int xb = blockIdx.x, bh = blockIdx.y, b = bh >> 3;
  const int lg = tid >> 4, cg = tid & 15;
  const float* kvb = kvg + (size_t)bh * KVSTRIDE;
  const float* qb = qin + (size_t)bh * S_LEN * 64;
  const int* mb = q_mask + b * S_LEN;

  // stage KV + ksum once per block (L2-resident, ~17KB)
#pragma unroll
  for (int i = 0; i < 4; ++i) {
    int f = tid + 256 * i;
    *(f32x4*)&kv_lds[f * 4] = *(const f32x4*)(kvb + (size_t)f * 4);
  }
  if (tid < 64) ks_lds[tid] = kvb[4096 + tid];

  f32x4 qr[4];
  float mr[4];

#define LOADQ(r0_)                                                     \
  {                                                                    \
    const float* qp_ = qb + (size_t)(r0_) * 64;                        \
    _Pragma("unroll")                                                  \
    for (int i_ = 0; i_ < 4; ++i_) {                                   \
      int f_ = tid + 256 * i_;                                         \
      qr[i_] = *(const f32x4*)(qp_ + (size_t)f_ * 4);                  \
      mr[i_] = mb[(r0_) + lg + 16 * i_] ? 1.0f : 0.0f;                 \
    }                                                                  \
  }

#define STOREQ(buf_)                                                   \
  {                                                                    \
    _Pragma("unroll")                                                  \
    for (int i_ = 0; i_ < 4; ++i_) {                                   \
      int row_ = lg + 16 * i_;                                         \
      float m_ = mr[i_];                                               \
      f32x4 qe_;                                                       \
      _Pragma("unroll")                                                \
      for (int j_ = 0; j_ < 4; ++j_) qe_[j_] = elu1(qr[i_][j_]) * m_;  \
      *(f32x4*)&qe_lds[buf_][row_ * 68 + cg * 4] = qe_;                \
    }                                                                  \
  }

  const int c0 = xb * 8;   // this block's 8 row-chunks
  LOADQ(c0 * 64)
  STOREQ(0)
  for (int t = 0; t < 8; ++t) {
    __syncthreads();
    if (t + 1 < 8) LOADQ((c0 + t + 1) * 64)
    float acc[4][4];
    float den[4];
#pragma unroll
    for (int il = 0; il < 4; ++il) {
      den[il] = 0.f;
#pragma unroll
      for (int j = 0; j < 4; ++j) acc[il][j] = 0.f;
    }
    const float* qbuf = qe_lds[t & 1];
#pragma unroll 8
    for (int d = 0; d < 64; d += 2) {
      float2 ksv = *(const float2*)&ks_lds[d];
      f32x4 kv0 = *(const f32x4*)&kv_lds[d * 64 + cg * 4];
      f32x4 kv1 = *(const f32x4*)&kv_lds[(d + 1) * 64 + cg * 4];
#pragma unroll
      for (int il = 0; il < 4; ++il) {
        float2 qv = *(const float2*)&qbuf[(lg * 4 + il) * 68 + d];
        den[il] = fmaf(qv.x, ksv.x, fmaf(qv.y, ksv.y, den[il]));
#pragma unroll
        for (int j = 0; j < 4; ++j)
          acc[il][j] = fmaf(qv.x, kv0[j], fmaf(qv.y, kv1[j], acc[il][j]));
      }
    }
    if (t + 1 < 8) STOREQ((t + 1) & 1)   // consume q loads after compute
    const int r0 = (c0 + t) * 64;
#pragma unroll
    for (int il = 0; il < 4; ++il) {
      float inv = 8192.0f / (den[il] + 1e-6f);
      int row = r0 + lg * 4 + il;
      f32x4 o;
#pragma unroll
      for (int j = 0; j < 4; ++j) o[j] = acc[il][j] * inv;
      *(f32x4*)(out + ((size_t)bh * S_LEN + row) * 64 + cg * 4) = o;
    }
  }
#undef LOADQ
#undef STOREQ
}

extern "C" void kernel_launch(void* const* d_in, const int* in_sizes, int n_in,
                              void* d_out, int out_size, void* d_ws, size_t ws_size,
                              hipStream_t stream) {
  const float* q = (const float*)d_in[0];
  const float* k = (const float*)d_in[1];
  const float* v = (const float*)d_in[2];
  const int* qm = (const int*)d_in[3];
  const int* km = (const int*)d_in[4];
  float* out = (float*)d_out;

  int nchunk = NCHUNK;
  while (nchunk > 1) {
    size_t need = (size_t)NBH * nchunk * KVSTRIDE * 4 + (size_t)NBH * KVSTRIDE * 4;
    if (need <= ws_size) break;
    nchunk >>= 1;
  }
  float* partials = (float*)d_ws;                           // [NBH][nchunk][KVSTRIDE]
  float* kvg = partials + (size_t)NBH * nchunk * KVSTRIDE;  // [NBH][KVSTRIDE]
  int seg_rows = S_LEN / nchunk;

  k1_partial<<<dim3(nchunk, NBH), 256, 0, stream>>>(k, v, km, partials, seg_rows);
  int n_elem = NBH * KVSTRIDE;
  k2_reduce<<<dim3((n_elem + 255) / 256), 256, 0, stream>>>(partials, kvg, nchunk);
  k3_out<<<dim3(K3_XB, NBH), 256, 0, stream>>>(q, qm, kvg, out);
}

// Round 3
// 255.726 us; speedup vs baseline: 1.0457x; 1.0457x over previous
//
#include <hip/hip_runtime.h>

// Linear attention, all-fp32, occupancy-first design.
// Per bh: KV[d][c] = sum_s ke[s][d]*ve[s][c]/S ; ksum[d] = sum_s ke[s][d]
//         out[l][c] = S * (qe.KV)[l][c] / (qe.ksum[l] + 1e-6)
//
// Lesson from r1/r2 A/B: at 2 blocks/CU (8 waves) every structure lands at
// 60-73 us (9000 cy/tile vs ~2100 cy of FMA issue). This version targets
// 4 blocks/CU (16 waves, launch_bounds(256,4), <=34KB LDS, 1024 blocks) with
// barrier-safe load placement: next tile's global loads are issued AFTER the
// post-store barrier and consumed AFTER compute, so the vmcnt(0) drain inside
// every __syncthreads happens ~2000 cycles after issue (free).

#define S_LEN 8192
#define NBH 32
#define KVSTRIDE 4160   // 4096 KV + 64 ksum per (bh, chunk)
#define NCHUNK 32       // k1: 1024 blocks, 4 tiles of 64 rows each
#define K3_XB 32        // k3: 1024 blocks, 4 chunks of 64 rows each

typedef __attribute__((ext_vector_type(4))) float f32x4;

__device__ __forceinline__ float elu1(float x) {
  return x > 0.0f ? (x + 1.0f) : __expf(x);
}

// ---------------- Phase 1: partial KV + ksum over a segment of S ----------------
// Thread tile 4(d) x 4(c). Single 32KB LDS buffer (5 blocks/CU LDS-wise).
// Per tile: sync_a (free drain) -> transform+store -> sync_b -> load t+1 -> compute.
__global__ __launch_bounds__(256, 4) void k1_partial(
    const float* __restrict__ kin, const float* __restrict__ vin,
    const int* __restrict__ kv_mask, float* __restrict__ partials, int seg_rows) {
  __shared__ float ke_lds[64 * 64];
  __shared__ float ve_lds[64 * 64];
  const int tid = threadIdx.x;
  const int seg = blockIdx.x, bh = blockIdx.y, b = bh >> 3;   // H=8
  const int rbase = seg * seg_rows;
  const int dg = tid >> 4, cg = tid & 15;
  const float* kbase = kin + (size_t)bh * S_LEN * 64;
  const float* vbase = vin + (size_t)bh * S_LEN * 64;
  const int* mbase = kv_mask + b * S_LEN;

  f32x4 kr[4], vr[4];
  float mr[4];
  float acc[4][4];
#pragma unroll
  for (int i = 0; i < 4; ++i)
#pragma unroll
    for (int j = 0; j < 4; ++j) acc[i][j] = 0.f;
  f32x4 ksump = {0.f, 0.f, 0.f, 0.f};

#define LOAD_T(r0_)                                                    \
  {                                                                    \
    const float* kp_ = kbase + (size_t)(r0_) * 64;                     \
    const float* vp_ = vbase + (size_t)(r0_) * 64;                     \
    _Pragma("unroll")                                                  \
    for (int i_ = 0; i_ < 4; ++i_) {                                   \
      int f_ = tid + 256 * i_;                                         \
      kr[i_] = *(const f32x4*)(kp_ + (size_t)f_ * 4);                  \
      vr[i_] = *(const f32x4*)(vp_ + (size_t)f_ * 4);                  \
      mr[i_] = mbase[(r0_) + dg + 16 * i_] ? 1.0f : 0.0f;              \
    }                                                                  \
  }

#define STORE_T()                                                      \
  {                                                                    \
    _Pragma("unroll")                                                  \
    for (int i_ = 0; i_ < 4; ++i_) {                                   \
      int row_ = dg + 16 * i_;                                         \
      float m_ = mr[i_];                                               \
      float mv_ = m_ * (1.0f / 8192.0f);                               \
      f32x4 ke4_, ve4_;                                                \
      _Pragma("unroll")                                                \
      for (int j_ = 0; j_ < 4; ++j_) {                                 \
        ke4_[j_] = elu1(kr[i_][j_]) * m_;                              \
        ve4_[j_] = vr[i_][j_] * mv_;                                   \
      }                                                                \
      ksump += ke4_;                                                   \
      *(f32x4*)&ke_lds[row_ * 64 + cg * 4] = ke4_;                     \
      *(f32x4*)&ve_lds[row_ * 64 + cg * 4] = ve4_;                     \
    }                                                                  \
  }

#define COMPUTE_T()                                                    \
  {                                                                    \
    _Pragma("unroll 4")                                                \
    for (int s_ = 0; s_ < 64; ++s_) {                                  \
      f32x4 kd_ = *(const f32x4*)&ke_lds[s_ * 64 + dg * 4];            \
      f32x4 vc_ = *(const f32x4*)&ve_lds[s_ * 64 + cg * 4];            \
      _Pragma("unroll")                                                \
      for (int i_ = 0; i_ < 4; ++i_)                                   \
        _Pragma("unroll")                                              \
        for (int j_ = 0; j_ < 4; ++j_)                                 \
          acc[i_][j_] = fmaf(kd_[i_], vc_[j_], acc[i_][j_]);           \
    }                                                                  \
  }

  const int ntiles = seg_rows >> 6;   // 4 at NCHUNK=32
  LOAD_T(rbase)
  for (int t = 0; t < ntiles; ++t) {
    if (t) __syncthreads();           // sync_a: loads for t issued one compute ago -> free drain
    STORE_T()                         // transform + LDS write (consumes loads)
    __syncthreads();                  // sync_b: nothing in flight, lgkm only
    if (t + 1 < ntiles) LOAD_T(rbase + (t + 1) * 64)
    COMPUTE_T()                       // ~2000+ cy, covers the loads above
  }

  // store partial KV [d][c] fp32 (coalesced float4)
  float* p = partials + ((size_t)bh * gridDim.x + seg) * KVSTRIDE;
#pragma unroll
  for (int i = 0; i < 4; ++i) {
    f32x4 o;
#pragma unroll
    for (int j = 0; j < 4; ++j) o[j] = acc[i][j];
    *(f32x4*)&p[(dg * 4 + i) * 64 + cg * 4] = o;
  }
  // ksum: reduce per-thread column partials (thread covers cols cg*4..+3)
  __syncthreads();
  *(f32x4*)&ke_lds[tid * 4] = ksump;
  __syncthreads();
  if (tid < 64) {
    float s = 0.f;
#pragma unroll
    for (int g = 0; g < 16; ++g)
      s += ke_lds[(g * 16 + (tid >> 2)) * 4 + (tid & 3)];
    p[4096 + tid] = s;
  }
#undef LOAD_T
#undef STORE_T
#undef COMPUTE_T
}

// ---------------- Phase 2: reduce partials -> fp32 KV + ksum ----------------
__global__ __launch_bounds__(256) void k2_reduce(
    const float* __restrict__ partials, float* __restrict__ kvg, int nchunk) {
  const int idx = blockIdx.x * 256 + threadIdx.x;
  if (idx >= NBH * KVSTRIDE) return;
  const int bh = idx / KVSTRIDE;
  const int e = idx - bh * KVSTRIDE;
  const float* p = partials + (size_t)bh * nchunk * KVSTRIDE + e;
  float s0 = 0.f, s1 = 0.f, s2 = 0.f, s3 = 0.f;
  int c = 0;
  for (; c + 4 <= nchunk; c += 4) {
    s0 += p[(size_t)(c + 0) * KVSTRIDE];
    s1 += p[(size_t)(c + 1) * KVSTRIDE];
    s2 += p[(size_t)(c + 2) * KVSTRIDE];
    s3 += p[(size_t)(c + 3) * KVSTRIDE];
  }
  for (; c < nchunk; ++c) s0 += p[(size_t)c * KVSTRIDE];
  kvg[idx] = (s0 + s1) + (s2 + s3);
}

// ---------------- Phase 3: out = S * (qe.KV) / (qe.ksum + 1e-6) ----------------
// 1024 blocks x 4 chunks. KV + ksum staged once per block (~16.5KB), qe single
// buffer (17.4KB, stride 68) -> ~34KB LDS, 4 blocks/CU. Same barrier-safe
// pipeline as k1. Denominator folded into the compute loop.
__global__ __launch_bounds__(256, 4) void k3_out(
    const float* __restrict__ qin, const int* __restrict__ q_mask,
    const float* __restrict__ kvg, float* __restrict__ out) {
  __shared__ float kv_lds[64 * 64];
  __shared__ float qe_lds[64 * 68];
  __shared__ float ks_lds[64];
  const int tid = threadIdx.x;
  const int xb = blockIdx.x, bh = blockIdx.y, b = bh >> 3;
  const int lg = tid >> 4, cg = tid & 15;
  const float* kvb = kvg + (size_t)bh * KVSTRIDE;
  const float* qb = qin + (size_t)bh * S_LEN * 64;
  const int* mb = q_mask + b * S_LEN;

  // stage KV + ksum once per block (L2-resident)
#pragma unroll
  for (int i = 0; i < 4; ++i) {
    int f = tid + 256 * i;
    *(f32x4*)&kv_lds[f * 4] = *(const f32x4*)(kvb + (size_t)f * 4);
  }
  if (tid < 64) ks_lds[tid] = kvb[4096 + tid];

  f32x4 qr[4];
  float mr[4];

#define LOADQ(r0_)                                                     \
  {                                                                    \
    const float* qp_ = qb + (size_t)(r0_) * 64;                        \
    _Pragma("unroll")                                                  \
    for (int i_ = 0; i_ < 4; ++i_) {                                   \
      int f_ = tid + 256 * i_;                                         \
      qr[i_] = *(const f32x4*)(qp_ + (size_t)f_ * 4);                  \
      mr[i_] = mb[(r0_) + lg + 16 * i_] ? 1.0f : 0.0f;                 \
    }                                                                  \
  }

#define STOREQ()                                                       \
  {                                                                    \
    _Pragma("unroll")                                                  \
    for (int i_ = 0; i_ < 4; ++i_) {                                   \
      int row_ = lg + 16 * i_;                                         \
      float m_ = mr[i_];                                               \
      f32x4 qe_;                                                       \
      _Pragma("unroll")                                                \
      for (int j_ = 0; j_ < 4; ++j_) qe_[j_] = elu1(qr[i_][j_]) * m_;  \
      *(f32x4*)&qe_lds[row_ * 68 + cg * 4] = qe_;                      \
    }                                                                  \
  }

  const int c0 = xb * 4;   // this block's 4 row-chunks
  LOADQ(c0 * 64)
  for (int t = 0; t < 4; ++t) {
    if (t) __syncthreads();           // sync_a: q loads + out stores aged one compute -> cheap drain
    STOREQ()
    __syncthreads();                  // sync_b: also makes kv_lds/ks_lds visible (t==0)
    if (t + 1 < 4) LOADQ((c0 + t + 1) * 64)
    float acc[4][4];
    float den[4];
#pragma unroll
    for (int il = 0; il < 4; ++il) {
      den[il] = 0.f;
#pragma unroll
      for (int j = 0; j < 4; ++j) acc[il][j] = 0.f;
    }
#pragma unroll 8
    for (int d = 0; d < 64; d += 2) {
      float2 ksv = *(const float2*)&ks_lds[d];
      f32x4 kv0 = *(const f32x4*)&kv_lds[d * 64 + cg * 4];
      f32x4 kv1 = *(const f32x4*)&kv_lds[(d + 1) * 64 + cg * 4];
#pragma unroll
      for (int il = 0; il < 4; ++il) {
        float2 qv = *(const float2*)&qe_lds[(lg * 4 + il) * 68 + d];
        den[il] = fmaf(qv.x, ksv.x, fmaf(qv.y, ksv.y, den[il]));
#pragma unroll
        for (int j = 0; j < 4; ++j)
          acc[il][j] = fmaf(qv.x, kv0[j], fmaf(qv.y, kv1[j], acc[il][j]));
      }
    }
    const int r0 = (c0 + t) * 64;
#pragma unroll
    for (int il = 0; il < 4; ++il) {
      float inv = 8192.0f / (den[il] + 1e-6f);
      int row = r0 + lg * 4 + il;
      f32x4 o;
#pragma unroll
      for (int j = 0; j < 4; ++j) o[j] = acc[il][j] * inv;
      *(f32x4*)(out + ((size_t)bh * S_LEN + row) * 64 + cg * 4) = o;
    }
  }
#undef LOADQ
#undef STOREQ
}

extern "C" void kernel_launch(void* const* d_in, const int* in_sizes, int n_in,
                              void* d_out, int out_size, void* d_ws, size_t ws_size,
                              hipStream_t stream) {
  const float* q = (const float*)d_in[0];
  const float* k = (const float*)d_in[1];
  const float* v = (const float*)d_in[2];
  const int* qm = (const int*)d_in[3];
  const int* km = (const int*)d_in[4];
  float* out = (float*)d_out;

  int nchunk = NCHUNK;
  while (nchunk > 1) {
    size_t need = (size_t)NBH * nchunk * KVSTRIDE * 4 + (size_t)NBH * KVSTRIDE * 4;
    if (need <= ws_size) break;
    nchunk >>= 1;
  }
  float* partials = (float*)d_ws;                           // [NBH][nchunk][KVSTRIDE]
  float* kvg = partials + (size_t)NBH * nchunk * KVSTRIDE;  // [NBH][KVSTRIDE]
  int seg_rows = S_LEN / nchunk;

  k1_partial<<<dim3(nchunk, NBH), 256, 0, stream>>>(k, v, km, partials, seg_rows);
  int n_elem = NBH * KVSTRIDE;
  k2_reduce<<<dim3((n_elem + 255) / 256), 256, 0, stream>>>(partials, kvg, nchunk);
  k3_out<<<dim3(K3_XB, NBH), 256, 0, stream>>>(q, qm, kvg, out);
}